// Round 5
// baseline (745.227 us; speedup 1.0000x reference)
//
#include <hip/hip_runtime.h>

#define TL 1024
#define NT 1023

typedef __bf16 bf16x8 __attribute__((ext_vector_type(8)));
typedef float  f32x4  __attribute__((ext_vector_type(4)));

__device__ __forceinline__ f32x4 mfma_bf16(bf16x8 a, bf16x8 b, f32x4 c) {
  return __builtin_amdgcn_mfma_f32_16x16x32_bf16(a, b, c, 0, 0, 0);
}

// pack bf16(e) into low16, bf16(o) into high16 (truncation)
__device__ __forceinline__ unsigned pk_hi(unsigned e, unsigned o) {
  return __builtin_amdgcn_perm(o, e, 0x07060302u);
}

__device__ __forceinline__ float fast_tanh(float x) {
  float e = __builtin_amdgcn_exp2f(x * 2.8853900817779268f);
  float r = __builtin_amdgcn_rcpf(e + 1.0f);
  return fmaf(-2.0f, r, 1.0f);
}

// split 8 fp32 (k-contiguous) into hi/lo bf16 fragments (truncation + residual)
__device__ __forceinline__ void split8(const float x[8], bf16x8& hi, bf16x8& lo) {
  unsigned h[4], l[4];
#pragma unroll
  for (int j = 0; j < 4; ++j) {
    unsigned eu = __float_as_uint(x[2 * j]);
    unsigned ou = __float_as_uint(x[2 * j + 1]);
    h[j] = pk_hi(eu, ou);
    float el = x[2 * j]     - __uint_as_float(eu & 0xFFFF0000u);
    float ol = x[2 * j + 1] - __uint_as_float(ou & 0xFFFF0000u);
    l[j] = pk_hi(__float_as_uint(el), __float_as_uint(ol));
  }
  hi = __builtin_bit_cast(bf16x8, make_uint4(h[0], h[1], h[2], h[3]));
  lo = __builtin_bit_cast(bf16x8, make_uint4(l[0], l[1], l[2], l[3]));
}

// compile-time element extraction from a 2x int4 / 2x float4 staging pair
static __device__ __forceinline__ int exti(const int4 v[2], int j) {
  const int4 w = v[j >> 2];
  return (j & 3) == 0 ? w.x : (j & 3) == 1 ? w.y : (j & 3) == 2 ? w.z : w.w;
}
static __device__ __forceinline__ float extf(const float4 v[2], int j) {
  const float4 w = v[j >> 2];
  return (j & 3) == 0 ? w.x : (j & 3) == 1 ? w.y : (j & 3) == 2 ? w.z : w.w;
}

// 6-MFMA recurrent product, EXACT round-0 serial association per accumulator
__device__ __forceinline__ void rec6(const bf16x8& Ah0, const bf16x8& Ah1,
                                     const bf16x8& Al0, const bf16x8& Al1,
                                     const bf16x8& Bh, const bf16x8& Bl,
                                     const f32x4& c0, const f32x4& c1,
                                     f32x4& o0, f32x4& o1) {
  f32x4 d0 = mfma_bf16(Ah0, Bh, c0);
  f32x4 d1 = mfma_bf16(Ah1, Bh, c1);
  d0 = mfma_bf16(Ah0, Bl, d0);
  d1 = mfma_bf16(Ah1, Bl, d1);
  d0 = mfma_bf16(Al0, Bh, d0);
  d1 = mfma_bf16(Al1, Bh, d1);
  o0 = d0;  o1 = d1;
}

// 3-MFMA head chain, EXACT round-0 association
__device__ __forceinline__ f32x4 head3(const bf16x8& Ah, const bf16x8& Al,
                                       const bf16x8& Bh, const bf16x8& Bl) {
  const f32x4 zf = {0.f, 0.f, 0.f, 0.f};
  f32x4 d = mfma_bf16(Ah, Bh, zf);
  d = mfma_bf16(Ah, Bl, d);
  d = mfma_bf16(Al, Bh, d);
  return d;
}

// tanh + repack (R module: no post-add)
__device__ __forceinline__ void tsR(const f32x4& p0, const f32x4& p1,
                                    bf16x8& Bh, bf16x8& Bl) {
  float x[8];
#pragma unroll
  for (int i = 0; i < 4; ++i) {
    x[i]     = fast_tanh(p0[i]);
    x[4 + i] = fast_tanh(p1[i]);
  }
  split8(x, Bh, Bl);
}

// tanh + repack (A module: + post-add table values)
__device__ __forceinline__ void tsA(const f32x4& p0, const f32x4& p1,
                                    const f32x4& q0, const f32x4& q1,
                                    bf16x8& Bh, bf16x8& Bl) {
  float x[8];
#pragma unroll
  for (int i = 0; i < 4; ++i) {
    x[i]     = fast_tanh(p0[i] + q0[i]);
    x[4 + i] = fast_tanh(p1[i] + q1[i]);
  }
  split8(x, Bh, Bl);
}

#define SB0() __builtin_amdgcn_sched_barrier(0)

// ---------------------------------------------------------------------------
// Anti-phase 2-group software pipeline. Evidence: halving per-wave work
// (r4) changed nothing and same-phase 2-group ILP (r1) filled nothing ->
// per-step time is serial phase-transition latency (rec->tanh->split->head->q),
// invariant to width. Fix: two batch groups per wave, half a step out of
// phase, so each group's dense work covers the other's transitions:
//   phase A(t): REC(g0,t) issue | TS(g1,t-1), HEAD(g1,t-1) issue, Q(g0,t-1)
//   phase B(t): REC(g1,t) issue | TS(g0,t),   HEAD(g0,t)   issue, Q(g1,t-1)
// sched_barrier(0) pins the phase boundaries (r1 showed the compiler
// otherwise re-clusters groups). Per-group op sequence is bit-identical to
// the verified round-0/4 kernels. Module split + LDS combine kept from r4:
// wave 0 = reward module + q + stores, wave 1 = action module -> cs to LDS,
// one barrier per 8-step chunk, double-buffered csb (cross-block atomics
// are broken on this part -- r2/r3).
// Both q and cs finalize lag one half-step, so chunk cI's slots/stores hold
// steps 8cI-1 .. 8cI+6 for BOTH groups (slot u = step 8cI+u-1).
// ---------------------------------------------------------------------------
__global__ __launch_bounds__(128, 1) void memann_kernel(
    const int* __restrict__ actions, const float* __restrict__ rewards,
    const float* __restrict__ w_r1, const float* __restrict__ b_r1,
    const float* __restrict__ w_r2, const float* __restrict__ b_r2,
    const float* __restrict__ w_a1, const float* __restrict__ b_a1,
    const float* __restrict__ w_a2, const float* __restrict__ b_a2,
    float* __restrict__ out) {
  const int tid = threadIdx.x;
  const int wid = tid >> 6;         // 0 = reward module, 1 = action module
  const int l   = tid & 63;
  const int b0  = blockIdx.x * 32;  // two 16-col groups per block
  const int m  = l & 15;            // A-frag: output-row index
  const int ga = l >> 4;            // A/B-frag: k-group
  const int c  = l & 15;            // D-frag: batch column
  const int gD = l >> 4;            // D-frag: row-group

  __shared__ __align__(16) float tbl[2][4][64][4];   // [half][action][lane][reg]
  __shared__ __align__(16) float csb[2][2][8][64];   // [buf][group][slot][lane]

  if (wid == 1) {
#pragma unroll
    for (int h = 0; h < 2; ++h)
#pragma unroll
      for (int a = 0; a < 4; ++a)
#pragma unroll
        for (int i = 0; i < 4; ++i) {
          const int row = 8 * gD + 4 * h + i;
          tbl[h][a][l][i] = b_a1[row] + w_a1[row * 36 + a];
        }
  }
  __syncthreads();

  const uint4 z4 = make_uint4(0u, 0u, 0u, 0u);
  const int rowA = 8 * (m >> 2) + (m & 3);  // pi(m, 0)
  float wt[8];

  const int* arow0 = actions + (size_t)(b0 + c) * TL;
  const int* arow1 = actions + (size_t)(b0 + 16 + c) * TL;

  if (wid == 0) {
    // ======== wave 0: reward module (2 groups, skewed) + q + stores ========
    bf16x8 AWh0, AWh1, AWl0, AWl1, AQh, AQl;
#pragma unroll
    for (int i = 0; i < 8; ++i) wt[i] = w_r1[rowA * 33 + 1 + 8 * ga + i];
    split8(wt, AWh0, AWl0);
#pragma unroll
    for (int i = 0; i < 8; ++i) wt[i] = w_r1[(rowA + 4) * 33 + 1 + 8 * ga + i];
    split8(wt, AWh1, AWl1);
#pragma unroll
    for (int i = 0; i < 8; ++i) wt[i] = w_r2[8 * ga + i];
    split8(wt, AQh, AQl);

    float br1p[8], wr0p[8];
#pragma unroll
    for (int i = 0; i < 4; ++i) {
      br1p[i]     = b_r1[8 * gD + i];
      wr0p[i]     = w_r1[(8 * gD + i) * 33];
      br1p[4 + i] = b_r1[8 * gD + 4 + i];
      wr0p[4 + i] = w_r1[(8 * gD + 4 + i) * 33];
    }
    const float br2  = b_r2[0];
    const float ba2g = b_a2[gD];

    const float* rrow0 = rewards + (size_t)(b0 + c) * TL;
    const float* rrow1 = rewards + (size_t)(b0 + 16 + c) * TL;
    float* outp0 = out + (size_t)(b0 + c) * NT * 4 + gD;
    float* outp1 = out + (size_t)(b0 + 16 + c) * NT * 4 + gD;

    int4   a0c[2], a0n[2], a1c[2], a1n[2];
    float4 r0c[2], r0n[2], r1c[2], r1n[2];
    a0c[0] = *(const int4*)(arow0);      a0c[1] = *(const int4*)(arow0 + 4);
    a1c[0] = *(const int4*)(arow1);      a1c[1] = *(const int4*)(arow1 + 4);
    r0c[0] = *(const float4*)(rrow0);    r0c[1] = *(const float4*)(rrow0 + 4);
    r1c[0] = *(const float4*)(rrow1);    r1c[1] = *(const float4*)(rrow1 + 4);
    a0n[0] = *(const int4*)(arow0 + 8);  a0n[1] = *(const int4*)(arow0 + 12);
    a1n[0] = *(const int4*)(arow1 + 8);  a1n[1] = *(const int4*)(arow1 + 12);
    r0n[0] = *(const float4*)(rrow0 + 8); r0n[1] = *(const float4*)(rrow0 + 12);
    r1n[0] = *(const float4*)(rrow1 + 8); r1n[1] = *(const float4*)(rrow1 + 12);

    bf16x8 Bh0 = __builtin_bit_cast(bf16x8, z4), Bl0 = Bh0;
    bf16x8 Bh1 = Bh0, Bl1 = Bh0;
    f32x4 pR00, pR01, pR10, pR11;   // pending rec results per group
    f32x4 dqp0, dqp1;               // pending head results per group
    float qv0 = 0.f, qv1 = 0.f;
    float qreg0[8], qreg1[8];
    int a_last0 = 0, a_last1 = 0;

    for (int cI = 0; cI < 128; ++cI) {
#pragma unroll
      for (int u = 0; u < 8; ++u) {
        const float rc0 = extf(r0c, u);
        const float rc1 = extf(r1c, u);
        const int aq0 = (u == 0) ? a_last0 : exti(a0c, u - 1);
        const int aq1 = (u == 0) ? a_last1 : exti(a1c, u - 1);

        // ---------------- phase A ----------------
        f32x4 c00, c01;
#pragma unroll
        for (int i = 0; i < 4; ++i) {
          c00[i] = fmaf(wr0p[i],     rc0, br1p[i]);
          c01[i] = fmaf(wr0p[4 + i], rc0, br1p[4 + i]);
        }
        rec6(AWh0, AWh1, AWl0, AWl1, Bh0, Bl0, c00, c01, pR00, pR01);
        if (u != 0 || cI != 0) {
          tsR(pR10, pR11, Bh1, Bl1);          // g1 state t-1
          dqp1 = head3(AQh, AQl, Bh1, Bl1);   // g1 head issue
          const float qn0 = dqp0[0] + br2;    // finalize g0 step t-1
          qv0 = (aq0 == gD) ? qn0 : qv0 * 0.95f;
          qreg0[u] = qv0;
        }
        SB0();

        // ---------------- phase B ----------------
        f32x4 c10, c11;
#pragma unroll
        for (int i = 0; i < 4; ++i) {
          c10[i] = fmaf(wr0p[i],     rc1, br1p[i]);
          c11[i] = fmaf(wr0p[4 + i], rc1, br1p[4 + i]);
        }
        rec6(AWh0, AWh1, AWl0, AWl1, Bh1, Bl1, c10, c11, pR10, pR11);
        tsR(pR00, pR01, Bh0, Bl0);            // g0 state t
        dqp0 = head3(AQh, AQl, Bh0, Bl0);     // g0 head issue
        if (u != 0 || cI != 0) {
          const float qn1 = dqp1[0] + br2;    // finalize g1 step t-1
          qv1 = (aq1 == gD) ? qn1 : qv1 * 0.95f;
          qreg1[u] = qv1;
        }
        SB0();
      }

      a_last0 = a0c[1].w;
      a_last1 = a1c[1].w;

      __syncthreads();  // A-wave's cs slots for this chunk are visible

      const float* cb0 = &csb[cI & 1][0][0][0];
      const float* cb1 = &csb[cI & 1][1][0][0];
#pragma unroll
      for (int u = 0; u < 8; ++u) {
        if (u != 0 || cI != 0) {
          const int tq = 8 * cI + u - 1;      // max 1022 < NT
          outp0[(size_t)tq * 4] = (qreg0[u] + cb0[u * 64 + l]) + ba2g;
          outp1[(size_t)tq * 4] = (qreg1[u] + cb1[u * 64 + l]) + ba2g;
        }
      }

      // rotate staging, prefetch next chunk (clamped)
      a0c[0] = a0n[0]; a0c[1] = a0n[1]; a1c[0] = a1n[0]; a1c[1] = a1n[1];
      r0c[0] = r0n[0]; r0c[1] = r0n[1]; r1c[0] = r1n[0]; r1c[1] = r1n[1];
      int tp = 8 * cI + 16;
      if (tp > TL - 8) tp = TL - 8;
      a0n[0] = *(const int4*)(arow0 + tp);  a0n[1] = *(const int4*)(arow0 + tp + 4);
      a1n[0] = *(const int4*)(arow1 + tp);  a1n[1] = *(const int4*)(arow1 + tp + 4);
      r0n[0] = *(const float4*)(rrow0 + tp); r0n[1] = *(const float4*)(rrow0 + tp + 4);
      r1n[0] = *(const float4*)(rrow1 + tp); r1n[1] = *(const float4*)(rrow1 + tp + 4);
    }
  } else {
    // ======== wave 1: action module (2 groups, skewed) -> cs to LDS ========
    bf16x8 AWh0, AWh1, AWl0, AWl1, ACh, ACl;
#pragma unroll
    for (int i = 0; i < 8; ++i) wt[i] = w_a1[rowA * 36 + 4 + 8 * ga + i];
    split8(wt, AWh0, AWl0);
#pragma unroll
    for (int i = 0; i < 8; ++i) wt[i] = w_a1[(rowA + 4) * 36 + 4 + 8 * ga + i];
    split8(wt, AWh1, AWl1);
#pragma unroll
    for (int i = 0; i < 8; ++i) wt[i] = w_a2[(m & 3) * 32 + 8 * ga + i];
    split8(wt, ACh, ACl);

    int4 a0c[2], a0n[2], a1c[2], a1n[2];
    a0c[0] = *(const int4*)(arow0);      a0c[1] = *(const int4*)(arow0 + 4);
    a1c[0] = *(const int4*)(arow1);      a1c[1] = *(const int4*)(arow1 + 4);
    a0n[0] = *(const int4*)(arow0 + 8);  a0n[1] = *(const int4*)(arow0 + 12);
    a1n[0] = *(const int4*)(arow1 + 8);  a1n[1] = *(const int4*)(arow1 + 12);

    bf16x8 Bh0 = __builtin_bit_cast(bf16x8, z4), Bl0 = Bh0;
    bf16x8 Bh1 = Bh0, Bl1 = Bh0;
    const f32x4 zf = {0.f, 0.f, 0.f, 0.f};
    f32x4 pA00, pA01, pA10, pA11;   // pending rec results per group
    f32x4 pa00, pa01, pa10, pa11;   // pending table values per group
    f32x4 dcp0, dcp1;               // pending c-head results per group

    for (int cI = 0; cI < 128; ++cI) {
      float* cw0 = &csb[cI & 1][0][0][0];
      float* cw1 = &csb[cI & 1][1][0][0];
#pragma unroll
      for (int u = 0; u < 8; ++u) {
        const int a0 = exti(a0c, u);
        const int a1 = exti(a1c, u);

        // ---------------- phase A ----------------
        pa00 = *(const f32x4*)&tbl[0][a0][l][0];   // g0 table read issue
        pa01 = *(const f32x4*)&tbl[1][a0][l][0];
        rec6(AWh0, AWh1, AWl0, AWl1, Bh0, Bl0, zf, zf, pA00, pA01);
        if (u != 0 || cI != 0) {
          tsA(pA10, pA11, pa10, pa11, Bh1, Bl1);  // g1 state t-1
          dcp1 = head3(ACh, ACl, Bh1, Bl1);       // g1 c-head issue
          const float cs0 = (gD & 2) ? ((gD & 1) ? dcp0[3] : dcp0[2])
                                     : ((gD & 1) ? dcp0[1] : dcp0[0]);
          cw0[u * 64 + l] = cs0;                  // g0 step t-1 -> slot u
        }
        SB0();

        // ---------------- phase B ----------------
        pa10 = *(const f32x4*)&tbl[0][a1][l][0];   // g1 table read issue
        pa11 = *(const f32x4*)&tbl[1][a1][l][0];
        rec6(AWh0, AWh1, AWl0, AWl1, Bh1, Bl1, zf, zf, pA10, pA11);
        tsA(pA00, pA01, pa00, pa01, Bh0, Bl0);     // g0 state t
        dcp0 = head3(ACh, ACl, Bh0, Bl0);          // g0 c-head issue
        if (u != 0 || cI != 0) {
          const float cs1 = (gD & 2) ? ((gD & 1) ? dcp1[3] : dcp1[2])
                                     : ((gD & 1) ? dcp1[1] : dcp1[0]);
          cw1[u * 64 + l] = cs1;                   // g1 step t-1 -> slot u
        }
        SB0();
      }

      __syncthreads();  // hand chunk cI to wave 0

      a0c[0] = a0n[0]; a0c[1] = a0n[1]; a1c[0] = a1n[0]; a1c[1] = a1n[1];
      int tp = 8 * cI + 16;
      if (tp > TL - 8) tp = TL - 8;
      a0n[0] = *(const int4*)(arow0 + tp);  a0n[1] = *(const int4*)(arow0 + tp + 4);
      a1n[0] = *(const int4*)(arow1 + tp);  a1n[1] = *(const int4*)(arow1 + tp + 4);
    }
  }
}

// ---------- launch ----------

extern "C" void kernel_launch(void* const* d_in, const int* in_sizes, int n_in,
                              void* d_out, int out_size, void* d_ws,
                              size_t ws_size, hipStream_t stream) {
  const int* actions = (const int*)d_in[0];
  const float* rewards = (const float*)d_in[1];
  const float* w_r1 = (const float*)d_in[2];
  const float* b_r1 = (const float*)d_in[3];
  const float* w_r2 = (const float*)d_in[4];
  const float* b_r2 = (const float*)d_in[5];
  const float* w_a1 = (const float*)d_in[6];
  const float* b_a1 = (const float*)d_in[7];
  const float* w_a2 = (const float*)d_in[8];
  const float* b_a2 = (const float*)d_in[9];
  float* out = (float*)d_out;

  const int B = in_sizes[0] / TL;       // 8192
  const int blocks = B / 32;            // 256 blocks x 2 waves (R, A), 2 groups each

  hipLaunchKernelGGL(memann_kernel, dim3(blocks), dim3(128), 0, stream,
                     actions, rewards, w_r1, b_r1, w_r2, b_r2, w_a1, b_a1,
                     w_a2, b_a2, out);
}